// Round 5
// baseline (352.045 us; speedup 1.0000x reference)
//
#include <hip/hip_runtime.h>
#include <hip/hip_bf16.h>
#include <cstdint>
#include <cstddef>

#define T_DIM 1024
#define S_DIM 1024
#define N_HEADS 32
#define D_HEAD 128

typedef __attribute__((ext_vector_type(8))) short short8;
typedef __attribute__((ext_vector_type(4))) float floatx4;

__device__ inline int pack_bf16(float a, float b) {
    __hip_bfloat162 h = __float22bfloat162_rn(make_float2(a, b));
    int r; __builtin_memcpy(&r, &h, 4); return r;
}
__device__ inline ushort f2b(float x) {
    __hip_bfloat16 h = __float2bfloat16(x);
    ushort u; __builtin_memcpy(&u, &h, 2); return u;
}
__device__ inline float b2f(ushort u) {
    unsigned int v = ((unsigned int)u) << 16;
    float f; __builtin_memcpy(&f, &v, 4); return f;
}

// ---------------------------------------------------------------------------
// Vt[n][d][s] bf16 <- V[n][s][d] fp32.  64s x 128d tile per block.
// ---------------------------------------------------------------------------
__global__ __launch_bounds__(256) void vt_kernel(const float* __restrict__ V,
                                                 ushort* __restrict__ Vt) {
    const int s0 = blockIdx.x * 64;
    const int n  = blockIdx.y;
    __shared__ float lds[128 * 65];    // [d][s], stride 65

    const int tid = threadIdx.x;
    const float* Vn = V + ((size_t)n * S_DIM + s0) * D_HEAD;

    #pragma unroll
    for (int it = 0; it < 8; ++it) {
        int idx = tid + it * 256;          // 2048 float4 tasks
        int d4 = idx & 31, s = idx >> 5;   // d fast for coalescing
        float4 v = *(const float4*)(Vn + (size_t)s * D_HEAD + d4 * 4);
        lds[(d4 * 4 + 0) * 65 + s] = v.x;
        lds[(d4 * 4 + 1) * 65 + s] = v.y;
        lds[(d4 * 4 + 2) * 65 + s] = v.z;
        lds[(d4 * 4 + 3) * 65 + s] = v.w;
    }
    __syncthreads();

    ushort* Vtn = Vt + (size_t)n * D_HEAD * S_DIM;
    #pragma unroll
    for (int it = 0; it < 4; ++it) {
        int idx = tid + it * 256;          // 1024 int4 tasks
        int sg = idx & 7, d = idx >> 3;    // sg fast for coalesced writes
        const float* src = &lds[d * 65 + sg * 8];
        int4 o;
        o.x = pack_bf16(src[0], src[1]);
        o.y = pack_bf16(src[2], src[3]);
        o.z = pack_bf16(src[4], src[5]);
        o.w = pack_bf16(src[6], src[7]);
        *(int4*)&Vtn[(size_t)d * S_DIM + s0 + sg * 8] = o;
    }
}

// ---------------------------------------------------------------------------
// K1: logits (bf16) via MFMA, 64x64 causal tiles.
// ---------------------------------------------------------------------------
__global__ __launch_bounds__(256, 2) void qk_mfma(const float* __restrict__ Q,
                                                  const float* __restrict__ K,
                                                  ushort* __restrict__ Lb) {
    const int st = blockIdx.x;
    const int tt = blockIdx.y;
    const int n  = blockIdx.z;
    if (st > tt) return;

    __shared__ int Qt[64 * 64];
    __shared__ int Kt[64 * 64];

    const int tid = threadIdx.x;
    const int wv = tid >> 6, ln = tid & 63;
    const int frow = ln & 15, quad = ln >> 4;

    const float* Qn = Q + ((size_t)n * T_DIM + (size_t)tt * 64) * D_HEAD;
    const float* Kn = K + ((size_t)n * S_DIM + (size_t)st * 64) * D_HEAD;

    #pragma unroll
    for (int rep = 0; rep < 8; ++rep) {
        int idx = tid + rep * 256;
        int row = idx >> 5;
        int c4  = (idx & 31) * 4;
        int p   = c4 >> 1;
        int kb  = p >> 4, w = p & 15;
        int swz = 4 * (row & 3);
        float4 q = *(const float4*)(Qn + (size_t)row * D_HEAD + c4);
        int2 qv; qv.x = pack_bf16(q.x, q.y); qv.y = pack_bf16(q.z, q.w);
        *(int2*)&Qt[row * 64 + kb * 16 + (w ^ swz)] = qv;
        float4 k = *(const float4*)(Kn + (size_t)row * D_HEAD + c4);
        int2 kv; kv.x = pack_bf16(k.x, k.y); kv.y = pack_bf16(k.z, k.w);
        *(int2*)&Kt[row * 64 + kb * 16 + (w ^ swz)] = kv;
    }
    __syncthreads();

    const int swz = 4 * (frow & 3);
    floatx4 acc[4] = {};
    #pragma unroll
    for (int kb = 0; kb < 4; ++kb) {
        const short8 af = *(const short8*)&Qt[(wv * 16 + frow) * 64 + kb * 16 + ((quad * 4) ^ swz)];
        #pragma unroll
        for (int si = 0; si < 4; ++si) {
            const short8 bf = *(const short8*)&Kt[(si * 16 + frow) * 64 + kb * 16 + ((quad * 4) ^ swz)];
            acc[si] = __builtin_amdgcn_mfma_f32_16x16x32_bf16(af, bf, acc[si], 0, 0, 0);
        }
    }

    const int tbase = tt * 64 + wv * 16 + quad * 4;
    #pragma unroll
    for (int si = 0; si < 4; ++si) {
        const int s = st * 64 + si * 16 + frow;
        #pragma unroll
        for (int r = 0; r < 4; ++r)
            Lb[((size_t)n * T_DIM + tbase + r) * S_DIM + s] = f2b(acc[si][r]);
    }
}

// ---------------------------------------------------------------------------
// Precompute per-position 32x32 mixing matrices (bf16, layout [pos][m][n])
// ---------------------------------------------------------------------------
__global__ __launch_bounds__(256) void mat_kernel(const float* __restrict__ sw,
                                                  const float* __restrict__ w1,
                                                  const float* __restrict__ w2,
                                                  const float* __restrict__ dd,
                                                  float idadd,
                                                  ushort* __restrict__ out) {
    const int t = blockIdx.x;
    const int tid = threadIdx.x;
    const int m = tid >> 3;
    const int n0 = (tid & 7) * 4;

    const float w2m0 = w2[t * 64 + m];
    const float w2m1 = w2[t * 64 + 32 + m];
    const float ddm  = dd[t * 32 + m];

    float v[4];
    #pragma unroll
    for (int j = 0; j < 4; ++j) {
        int n = n0 + j;
        float r = w1[t * 64 + n] * w2m0 + w1[t * 64 + 32 + n] * w2m1;
        if (sw) r += sw[n * 32 + m];
        if (n == m) r += idadd + ddm;
        v[j] = r;
    }
    int p0 = pack_bf16(v[0], v[1]);
    int p1 = pack_bf16(v[2], v[3]);
    int2 st = make_int2(p0, p1);
    *(int2*)&out[(size_t)t * 1024 + m * 32 + n0] = st;
}

// ---------------------------------------------------------------------------
// Fused cross-head projection via MFMA, in place on bf16 L.
// ---------------------------------------------------------------------------
__global__ __launch_bounds__(256, 2) void proj_mfma(ushort* __restrict__ Lb,
                                                    const ushort* __restrict__ Cmat,
                                                    const ushort* __restrict__ Kmat) {
    const int s0 = blockIdx.x * 16;
    const int t0 = blockIdx.y * 32;
    if (s0 > t0 + 31) return;

    __shared__ __align__(16) int lds[8192 + 10368];
    int* tileA = lds;
    int* tileB = lds + 8192;
    int* ldsD  = lds + 8192;

    const int tid = threadIdx.x;
    const int wv = tid >> 6, ln = tid & 63;

    #pragma unroll
    for (int rep = 0; rep < 2; ++rep) {
        int p  = tid + rep * 256;
        int tl = p >> 4, sl = p & 15;
        const ushort* xp = Lb + (size_t)(t0 + tl) * S_DIM + (s0 + sl);
        int packed[16];
        #pragma unroll
        for (int h = 0; h < 16; ++h) {
            ushort a = xp[(size_t)(2 * h)     * (T_DIM * S_DIM)];
            ushort b = xp[(size_t)(2 * h + 1) * (T_DIM * S_DIM)];
            packed[h] = (int)a | ((int)b << 16);
        }
        const int baseA = (tl * 16 + sl) * 16, swA = 4 * (sl & 3);
        const int baseB = sl * 516 + tl * 16,  swB = 4 * (tl & 3);
        #pragma unroll
        for (int h = 0; h < 16; ++h) {
            tileA[baseA + (h ^ swA)] = packed[h];
            tileB[baseB + (h ^ swB)] = packed[h];
        }
    }
    __syncthreads();

    const int frow = ln & 15;
    const int fkg  = ln >> 4;

    floatx4 dk[4][2][2];
    #pragma unroll
    for (int si = 0; si < 4; ++si) {
        const int s_l = wv * 4 + si;
        const int s_g = s0 + s_l;
        #pragma unroll
        for (int mh = 0; mh < 2; ++mh) {
            const short8 af = *(const short8*)(Kmat + (size_t)s_g * 1024 + (mh * 16 + frow) * 32 + fkg * 8);
            #pragma unroll
            for (int tc = 0; tc < 2; ++tc) {
                const int* bp = &tileB[s_l * 516 + (tc * 16 + frow) * 16 + ((4 * fkg) ^ (4 * (frow & 3)))];
                const short8 bf = *(const short8*)bp;
                floatx4 z = {0.f, 0.f, 0.f, 0.f};
                dk[si][mh][tc] = __builtin_amdgcn_mfma_f32_16x16x32_bf16(af, bf, z, 0, 0, 0);
            }
        }
    }
    __syncthreads();

    #pragma unroll
    for (int mh = 0; mh < 2; ++mh) {
        #pragma unroll
        for (int si = 0; si < 4; ++si) {
            const int s_l = wv * 4 + si;
            #pragma unroll
            for (int tc = 0; tc < 2; ++tc) {
                const int tl = tc * 16 + frow;
                const int off = tl * 324 + s_l * 20 + fkg * 4;
                *(floatx4*)&ldsD[off] = dk[si][mh][tc];
            }
        }
        __syncthreads();

        #pragma unroll
        for (int ti = 0; ti < 8; ++ti) {
            const int tl = wv * 8 + ti;
            const int tg = t0 + tl;
            const short8 af = *(const short8*)&tileA[(tl * 16 + frow) * 16 + ((4 * fkg) ^ (4 * (frow & 3)))];
            const short8 bf = *(const short8*)(Cmat + (size_t)tg * 1024 + (mh * 16 + frow) * 32 + fkg * 8);
            floatx4 z = {0.f, 0.f, 0.f, 0.f};
            floatx4 d = __builtin_amdgcn_mfma_f32_16x16x32_bf16(af, bf, z, 0, 0, 0);

            const int m_l = frow;
            const int s_base = fkg * 4;
            float v[4];
            #pragma unroll
            for (int r = 0; r < 4; ++r) {
                float kadd = ((const float*)ldsD)[tl * 324 + (s_base + r) * 20 + m_l];
                float val = d[r] + kadd;
                v[r] = (s0 + s_base + r > tg) ? 0.0f : val;
            }
            uint2 st;
            st.x = (unsigned)pack_bf16(v[0], v[1]);
            st.y = (unsigned)pack_bf16(v[2], v[3]);
            *(uint2*)&Lb[((size_t)(mh * 16 + m_l) * T_DIM + tg) * S_DIM + s0 + s_base] = st;
        }
        __syncthreads();
    }
}

// ---------------------------------------------------------------------------
// K3: softmax over s in [0, t] per (n,t) row, in place on bf16 L.
// ---------------------------------------------------------------------------
__global__ __launch_bounds__(256) void softmax_kernel(ushort* __restrict__ Lb) {
    const int t = blockIdx.x;
    const int n = blockIdx.y;
    ushort* row = Lb + ((size_t)n * T_DIM + t) * S_DIM;
    const int tid = threadIdx.x;
    const int i0 = tid * 4;

    uint2 raw = *(const uint2*)&row[i0];
    float v[4];
    v[0] = b2f((ushort)(raw.x & 0xffff));
    v[1] = b2f((ushort)(raw.x >> 16));
    v[2] = b2f((ushort)(raw.y & 0xffff));
    v[3] = b2f((ushort)(raw.y >> 16));
    #pragma unroll
    for (int j = 0; j < 4; ++j)
        if (i0 + j > t) v[j] = -INFINITY;

    float m = fmaxf(fmaxf(v[0], v[1]), fmaxf(v[2], v[3]));
    #pragma unroll
    for (int off = 32; off > 0; off >>= 1) m = fmaxf(m, __shfl_xor(m, off));

    __shared__ float redm[4];
    __shared__ float reds[4];
    if ((tid & 63) == 0) redm[tid >> 6] = m;
    __syncthreads();
    m = fmaxf(fmaxf(redm[0], redm[1]), fmaxf(redm[2], redm[3]));

    float e[4];
    float ssum = 0.0f;
    #pragma unroll
    for (int j = 0; j < 4; ++j) {
        e[j] = (i0 + j <= t) ? expf(v[j] - m) : 0.0f;
        ssum += e[j];
    }
    #pragma unroll
    for (int off = 32; off > 0; off >>= 1) ssum += __shfl_xor(ssum, off);
    if ((tid & 63) == 0) reds[tid >> 6] = ssum;
    __syncthreads();
    ssum = reds[0] + reds[1] + reds[2] + reds[3];
    const float inv = 1.0f / ssum;

    uint2 st;
    st.x = (unsigned)pack_bf16(e[0] * inv, e[1] * inv);
    st.y = (unsigned)pack_bf16(e[2] * inv, e[3] * inv);
    *(uint2*)&row[i0] = st;
}

// ---------------------------------------------------------------------------
// K5: O = P V via MFMA, no LDS, no barriers. One wave per (n, 16-t tile).
// A-frag: P bf16 [t][s] contiguous; B-frag: Vt bf16 [d][s] contiguous.
// Causal mask applied in-register on steps touching the diagonal.
// ---------------------------------------------------------------------------
__global__ __launch_bounds__(64, 4) void av_mfma(const ushort* __restrict__ P,
                                                 const ushort* __restrict__ Vt,
                                                 float* __restrict__ O) {
    const int tt = 63 - blockIdx.x;      // big tiles first
    const int n  = blockIdx.y;
    const int t0 = tt * 16;

    const int ln = threadIdx.x & 63;
    const int frow = ln & 15, quad = ln >> 4;

    const ushort* Pn  = P  + ((size_t)n * T_DIM + t0) * S_DIM;
    const ushort* Vtn = Vt + (size_t)n * D_HEAD * S_DIM;

    const int nsteps = (t0 + 47) >> 5;   // ceil((t0+16)/32)
    const int nclean = t0 >> 5;          // steps fully below diagonal

    floatx4 acc[8] = {};

    for (int sb = 0; sb < nsteps; ++sb) {
        const int sbase = sb * 32;
        short8 a = *(const short8*)(Pn + (size_t)frow * S_DIM + sbase + quad * 8);
        if (sb >= nclean) {
            const int t = t0 + frow;
            #pragma unroll
            for (int j = 0; j < 8; ++j)
                if (sbase + quad * 8 + j > t) a[j] = 0;
        }
        #pragma unroll
        for (int dc = 0; dc < 8; ++dc) {
            const short8 b = *(const short8*)(Vtn + (size_t)(dc * 16 + frow) * S_DIM + sbase + quad * 8);
            acc[dc] = __builtin_amdgcn_mfma_f32_16x16x32_bf16(a, b, acc[dc], 0, 0, 0);
        }
    }

    #pragma unroll
    for (int dc = 0; dc < 8; ++dc)
        #pragma unroll
        for (int r = 0; r < 4; ++r)
            O[((size_t)n * T_DIM + t0 + quad * 4 + r) * D_HEAD + dc * 16 + frow] = acc[dc][r];
}

// ---------------------------------------------------------------------------
extern "C" void kernel_launch(void* const* d_in, const int* in_sizes, int n_in,
                              void* d_out, int out_size, void* d_ws, size_t ws_size,
                              hipStream_t stream) {
    const float* Q    = (const float*)d_in[0];
    const float* K    = (const float*)d_in[1];
    const float* V    = (const float*)d_in[2];
    const float* sw_pre  = (const float*)d_in[4];
    const float* qw1_pre = (const float*)d_in[5];
    const float* qw2_pre = (const float*)d_in[6];
    const float* kw1_pre = (const float*)d_in[7];
    const float* kw2_pre = (const float*)d_in[8];
    const float* qdd_pre = (const float*)d_in[9];
    const float* kdd_pre = (const float*)d_in[10];
    const float* sw_post  = (const float*)d_in[11];
    const float* qw1_post = (const float*)d_in[12];
    const float* qw2_post = (const float*)d_in[13];
    const float* kw1_post = (const float*)d_in[14];
    const float* kw2_post = (const float*)d_in[15];
    const float* qdd_post = (const float*)d_in[16];
    const float* kdd_post = (const float*)d_in[17];

    // ws: L bf16 [32][1024][1024] = 64 MB, then Vt bf16 [32][128][1024] = 8 MB
    ushort* Lb = (ushort*)d_ws;
    ushort* Vt = (ushort*)((char*)d_ws + (size_t)N_HEADS * T_DIM * S_DIM * 2);
    float*  O  = (float*)d_out;

    // mats in d_out (8 MB of 16), consumed before av overwrites d_out
    ushort* mats  = (ushort*)d_out;
    ushort* Cpre  = mats + 0 * 1024 * 1024;
    ushort* Kpre  = mats + 1 * 1024 * 1024;
    ushort* Cpost = mats + 2 * 1024 * 1024;
    ushort* Kpost = mats + 3 * 1024 * 1024;

    mat_kernel<<<1024, 256, 0, stream>>>(sw_pre,  qw1_pre,  qw2_pre,  qdd_pre,  1.0f, Cpre);
    mat_kernel<<<1024, 256, 0, stream>>>(nullptr, kw1_pre,  kw2_pre,  kdd_pre,  0.0f, Kpre);
    mat_kernel<<<1024, 256, 0, stream>>>(sw_post, qw1_post, qw2_post, qdd_post, 1.0f, Cpost);
    mat_kernel<<<1024, 256, 0, stream>>>(nullptr, kw1_post, kw2_post, kdd_post, 0.0f, Kpost);
    vt_kernel<<<dim3(16, 32), 256, 0, stream>>>(V, Vt);

    qk_mfma<<<dim3(16, 16, 32), 256, 0, stream>>>(Q, K, Lb);
    proj_mfma<<<dim3(64, 32), 256, 0, stream>>>(Lb, Cpre, Kpre);
    softmax_kernel<<<dim3(1024, 32), 256, 0, stream>>>(Lb);
    proj_mfma<<<dim3(64, 32), 256, 0, stream>>>(Lb, Cpost, Kpost);
    av_mfma<<<dim3(64, 32), 64, 0, stream>>>(Lb, Vt, O);
}

// Round 6
// 342.987 us; speedup vs baseline: 1.0264x; 1.0264x over previous
//
#include <hip/hip_runtime.h>
#include <hip/hip_bf16.h>
#include <cstdint>
#include <cstddef>

#define T_DIM 1024
#define S_DIM 1024
#define N_HEADS 32
#define D_HEAD 128

typedef __attribute__((ext_vector_type(8))) short short8;
typedef __attribute__((ext_vector_type(4))) float floatx4;

__device__ inline int pack_bf16(float a, float b) {
    __hip_bfloat162 h = __float22bfloat162_rn(make_float2(a, b));
    int r; __builtin_memcpy(&r, &h, 4); return r;
}
__device__ inline ushort f2b(float x) {
    __hip_bfloat16 h = __float2bfloat16(x);
    ushort u; __builtin_memcpy(&u, &h, 2); return u;
}
__device__ inline float b2f(ushort u) {
    unsigned int v = ((unsigned int)u) << 16;
    float f; __builtin_memcpy(&f, &v, 4); return f;
}

// ---------------------------------------------------------------------------
// Vt[n][d][s] bf16 <- V[n][s][d] fp32.  64s x 128d tile per block.
// ---------------------------------------------------------------------------
__global__ __launch_bounds__(256) void vt_kernel(const float* __restrict__ V,
                                                 ushort* __restrict__ Vt) {
    const int s0 = blockIdx.x * 64;
    const int n  = blockIdx.y;
    __shared__ float lds[128 * 65];

    const int tid = threadIdx.x;
    const float* Vn = V + ((size_t)n * S_DIM + s0) * D_HEAD;

    #pragma unroll
    for (int it = 0; it < 8; ++it) {
        int idx = tid + it * 256;
        int d4 = idx & 31, s = idx >> 5;
        float4 v = *(const float4*)(Vn + (size_t)s * D_HEAD + d4 * 4);
        lds[(d4 * 4 + 0) * 65 + s] = v.x;
        lds[(d4 * 4 + 1) * 65 + s] = v.y;
        lds[(d4 * 4 + 2) * 65 + s] = v.z;
        lds[(d4 * 4 + 3) * 65 + s] = v.w;
    }
    __syncthreads();

    ushort* Vtn = Vt + (size_t)n * D_HEAD * S_DIM;
    #pragma unroll
    for (int it = 0; it < 4; ++it) {
        int idx = tid + it * 256;
        int sg = idx & 7, d = idx >> 3;
        const float* src = &lds[d * 65 + sg * 8];
        int4 o;
        o.x = pack_bf16(src[0], src[1]);
        o.y = pack_bf16(src[2], src[3]);
        o.z = pack_bf16(src[4], src[5]);
        o.w = pack_bf16(src[6], src[7]);
        *(int4*)&Vtn[(size_t)d * S_DIM + s0 + sg * 8] = o;
    }
}

// ---------------------------------------------------------------------------
// K1: logits (bf16) via MFMA, 64x64 causal tiles.
// ---------------------------------------------------------------------------
__global__ __launch_bounds__(256, 2) void qk_mfma(const float* __restrict__ Q,
                                                  const float* __restrict__ K,
                                                  ushort* __restrict__ Lb) {
    const int st = blockIdx.x;
    const int tt = blockIdx.y;
    const int n  = blockIdx.z;
    if (st > tt) return;

    __shared__ int Qt[64 * 64];
    __shared__ int Kt[64 * 64];

    const int tid = threadIdx.x;
    const int wv = tid >> 6, ln = tid & 63;
    const int frow = ln & 15, quad = ln >> 4;

    const float* Qn = Q + ((size_t)n * T_DIM + (size_t)tt * 64) * D_HEAD;
    const float* Kn = K + ((size_t)n * S_DIM + (size_t)st * 64) * D_HEAD;

    #pragma unroll
    for (int rep = 0; rep < 8; ++rep) {
        int idx = tid + rep * 256;
        int row = idx >> 5;
        int c4  = (idx & 31) * 4;
        int p   = c4 >> 1;
        int kb  = p >> 4, w = p & 15;
        int swz = 4 * (row & 3);
        float4 q = *(const float4*)(Qn + (size_t)row * D_HEAD + c4);
        int2 qv; qv.x = pack_bf16(q.x, q.y); qv.y = pack_bf16(q.z, q.w);
        *(int2*)&Qt[row * 64 + kb * 16 + (w ^ swz)] = qv;
        float4 k = *(const float4*)(Kn + (size_t)row * D_HEAD + c4);
        int2 kv; kv.x = pack_bf16(k.x, k.y); kv.y = pack_bf16(k.z, k.w);
        *(int2*)&Kt[row * 64 + kb * 16 + (w ^ swz)] = kv;
    }
    __syncthreads();

    const int swz = 4 * (frow & 3);
    floatx4 acc[4] = {};
    #pragma unroll
    for (int kb = 0; kb < 4; ++kb) {
        const short8 af = *(const short8*)&Qt[(wv * 16 + frow) * 64 + kb * 16 + ((quad * 4) ^ swz)];
        #pragma unroll
        for (int si = 0; si < 4; ++si) {
            const short8 bf = *(const short8*)&Kt[(si * 16 + frow) * 64 + kb * 16 + ((quad * 4) ^ swz)];
            acc[si] = __builtin_amdgcn_mfma_f32_16x16x32_bf16(af, bf, acc[si], 0, 0, 0);
        }
    }

    const int tbase = tt * 64 + wv * 16 + quad * 4;
    #pragma unroll
    for (int si = 0; si < 4; ++si) {
        const int s = st * 64 + si * 16 + frow;
        #pragma unroll
        for (int r = 0; r < 4; ++r)
            Lb[((size_t)n * T_DIM + tbase + r) * S_DIM + s] = f2b(acc[si][r]);
    }
}

// ---------------------------------------------------------------------------
// Precompute all four 32x32 mixing-matrix families in one launch.
// blockIdx.y selects {Cpre, Kpre, Cpost, Kpost}. Layout [pos][m][n] bf16.
// ---------------------------------------------------------------------------
__global__ __launch_bounds__(256) void mat4_kernel(
        const float* __restrict__ sw_pre,  const float* __restrict__ qw1_pre,
        const float* __restrict__ qw2_pre, const float* __restrict__ qdd_pre,
        const float* __restrict__ kw1_pre, const float* __restrict__ kw2_pre,
        const float* __restrict__ kdd_pre,
        const float* __restrict__ sw_post,  const float* __restrict__ qw1_post,
        const float* __restrict__ qw2_post, const float* __restrict__ qdd_post,
        const float* __restrict__ kw1_post, const float* __restrict__ kw2_post,
        const float* __restrict__ kdd_post,
        ushort* __restrict__ mats) {
    const float *sw, *w1, *w2, *dd;
    float idadd;
    switch (blockIdx.y) {
        case 0:  sw = sw_pre;  w1 = qw1_pre;  w2 = qw2_pre;  dd = qdd_pre;  idadd = 1.0f; break;
        case 1:  sw = nullptr; w1 = kw1_pre;  w2 = kw2_pre;  dd = kdd_pre;  idadd = 0.0f; break;
        case 2:  sw = sw_post; w1 = qw1_post; w2 = qw2_post; dd = qdd_post; idadd = 1.0f; break;
        default: sw = nullptr; w1 = kw1_post; w2 = kw2_post; dd = kdd_post; idadd = 0.0f; break;
    }
    ushort* out = mats + (size_t)blockIdx.y * 1024 * 1024;

    const int t = blockIdx.x;
    const int tid = threadIdx.x;
    const int m = tid >> 3;
    const int n0 = (tid & 7) * 4;

    const float w2m0 = w2[t * 64 + m];
    const float w2m1 = w2[t * 64 + 32 + m];
    const float ddm  = dd[t * 32 + m];

    float v[4];
    #pragma unroll
    for (int j = 0; j < 4; ++j) {
        int n = n0 + j;
        float r = w1[t * 64 + n] * w2m0 + w1[t * 64 + 32 + n] * w2m1;
        if (sw) r += sw[n * 32 + m];
        if (n == m) r += idadd + ddm;
        v[j] = r;
    }
    int p0 = pack_bf16(v[0], v[1]);
    int p1 = pack_bf16(v[2], v[3]);
    int2 st = make_int2(p0, p1);
    *(int2*)&out[(size_t)t * 1024 + m * 32 + n0] = st;
}

// ---------------------------------------------------------------------------
// Fused cross-head projection via MFMA, in place on bf16 L.
// ---------------------------------------------------------------------------
__global__ __launch_bounds__(256, 2) void proj_mfma(ushort* __restrict__ Lb,
                                                    const ushort* __restrict__ Cmat,
                                                    const ushort* __restrict__ Kmat) {
    const int s0 = blockIdx.x * 16;
    const int t0 = blockIdx.y * 32;
    if (s0 > t0 + 31) return;

    __shared__ __align__(16) int lds[8192 + 10368];
    int* tileA = lds;
    int* tileB = lds + 8192;
    int* ldsD  = lds + 8192;

    const int tid = threadIdx.x;
    const int wv = tid >> 6, ln = tid & 63;

    #pragma unroll
    for (int rep = 0; rep < 2; ++rep) {
        int p  = tid + rep * 256;
        int tl = p >> 4, sl = p & 15;
        const ushort* xp = Lb + (size_t)(t0 + tl) * S_DIM + (s0 + sl);
        int packed[16];
        #pragma unroll
        for (int h = 0; h < 16; ++h) {
            ushort a = xp[(size_t)(2 * h)     * (T_DIM * S_DIM)];
            ushort b = xp[(size_t)(2 * h + 1) * (T_DIM * S_DIM)];
            packed[h] = (int)a | ((int)b << 16);
        }
        const int baseA = (tl * 16 + sl) * 16, swA = 4 * (sl & 3);
        const int baseB = sl * 516 + tl * 16,  swB = 4 * (tl & 3);
        #pragma unroll
        for (int h = 0; h < 16; ++h) {
            tileA[baseA + (h ^ swA)] = packed[h];
            tileB[baseB + (h ^ swB)] = packed[h];
        }
    }
    __syncthreads();

    const int frow = ln & 15;
    const int fkg  = ln >> 4;

    floatx4 dk[4][2][2];
    #pragma unroll
    for (int si = 0; si < 4; ++si) {
        const int s_l = wv * 4 + si;
        const int s_g = s0 + s_l;
        #pragma unroll
        for (int mh = 0; mh < 2; ++mh) {
            const short8 af = *(const short8*)(Kmat + (size_t)s_g * 1024 + (mh * 16 + frow) * 32 + fkg * 8);
            #pragma unroll
            for (int tc = 0; tc < 2; ++tc) {
                const int* bp = &tileB[s_l * 516 + (tc * 16 + frow) * 16 + ((4 * fkg) ^ (4 * (frow & 3)))];
                const short8 bf = *(const short8*)bp;
                floatx4 z = {0.f, 0.f, 0.f, 0.f};
                dk[si][mh][tc] = __builtin_amdgcn_mfma_f32_16x16x32_bf16(af, bf, z, 0, 0, 0);
            }
        }
    }
    __syncthreads();

    #pragma unroll
    for (int mh = 0; mh < 2; ++mh) {
        #pragma unroll
        for (int si = 0; si < 4; ++si) {
            const int s_l = wv * 4 + si;
            #pragma unroll
            for (int tc = 0; tc < 2; ++tc) {
                const int tl = tc * 16 + frow;
                const int off = tl * 324 + s_l * 20 + fkg * 4;
                *(floatx4*)&ldsD[off] = dk[si][mh][tc];
            }
        }
        __syncthreads();

        #pragma unroll
        for (int ti = 0; ti < 8; ++ti) {
            const int tl = wv * 8 + ti;
            const int tg = t0 + tl;
            const short8 af = *(const short8*)&tileA[(tl * 16 + frow) * 16 + ((4 * fkg) ^ (4 * (frow & 3)))];
            const short8 bf = *(const short8*)(Cmat + (size_t)tg * 1024 + (mh * 16 + frow) * 32 + fkg * 8);
            floatx4 z = {0.f, 0.f, 0.f, 0.f};
            floatx4 d = __builtin_amdgcn_mfma_f32_16x16x32_bf16(af, bf, z, 0, 0, 0);

            const int m_l = frow;
            const int s_base = fkg * 4;
            float v[4];
            #pragma unroll
            for (int r = 0; r < 4; ++r) {
                float kadd = ((const float*)ldsD)[tl * 324 + (s_base + r) * 20 + m_l];
                float val = d[r] + kadd;
                v[r] = (s0 + s_base + r > tg) ? 0.0f : val;
            }
            uint2 st;
            st.x = (unsigned)pack_bf16(v[0], v[1]);
            st.y = (unsigned)pack_bf16(v[2], v[3]);
            *(uint2*)&Lb[((size_t)(mh * 16 + m_l) * T_DIM + tg) * S_DIM + s0 + s_base] = st;
        }
        __syncthreads();
    }
}

// ---------------------------------------------------------------------------
// K3: softmax over s in [0, t] per (n,t) row, in place on bf16 L.
// ---------------------------------------------------------------------------
__global__ __launch_bounds__(256) void softmax_kernel(ushort* __restrict__ Lb) {
    const int t = blockIdx.x;
    const int n = blockIdx.y;
    ushort* row = Lb + ((size_t)n * T_DIM + t) * S_DIM;
    const int tid = threadIdx.x;
    const int i0 = tid * 4;

    uint2 raw = *(const uint2*)&row[i0];
    float v[4];
    v[0] = b2f((ushort)(raw.x & 0xffff));
    v[1] = b2f((ushort)(raw.x >> 16));
    v[2] = b2f((ushort)(raw.y & 0xffff));
    v[3] = b2f((ushort)(raw.y >> 16));
    #pragma unroll
    for (int j = 0; j < 4; ++j)
        if (i0 + j > t) v[j] = -INFINITY;

    float m = fmaxf(fmaxf(v[0], v[1]), fmaxf(v[2], v[3]));
    #pragma unroll
    for (int off = 32; off > 0; off >>= 1) m = fmaxf(m, __shfl_xor(m, off));

    __shared__ float redm[4];
    __shared__ float reds[4];
    if ((tid & 63) == 0) redm[tid >> 6] = m;
    __syncthreads();
    m = fmaxf(fmaxf(redm[0], redm[1]), fmaxf(redm[2], redm[3]));

    float e[4];
    float ssum = 0.0f;
    #pragma unroll
    for (int j = 0; j < 4; ++j) {
        e[j] = (i0 + j <= t) ? expf(v[j] - m) : 0.0f;
        ssum += e[j];
    }
    #pragma unroll
    for (int off = 32; off > 0; off >>= 1) ssum += __shfl_xor(ssum, off);
    if ((tid & 63) == 0) reds[tid >> 6] = ssum;
    __syncthreads();
    ssum = reds[0] + reds[1] + reds[2] + reds[3];
    const float inv = 1.0f / ssum;

    uint2 st;
    st.x = (unsigned)pack_bf16(e[0] * inv, e[1] * inv);
    st.y = (unsigned)pack_bf16(e[2] * inv, e[3] * inv);
    *(uint2*)&row[i0] = st;
}

// ---------------------------------------------------------------------------
// K5: O = P V via MFMA. Block = 4 waves over one (n, 16-t) tile; the s-range
// is split round-robin across the 4 waves (restores parallelism: 8192 waves),
// partials reduced through LDS, coalesced float4 stores by all threads.
// A-frag: P bf16 [t][s] contiguous; B-frag: Vt bf16 [d][s] contiguous.
// ---------------------------------------------------------------------------
__global__ __launch_bounds__(256, 4) void av_mfma(const ushort* __restrict__ P,
                                                  const ushort* __restrict__ Vt,
                                                  float* __restrict__ O) {
    const int tt = 63 - blockIdx.x;      // big tiles first
    const int n  = blockIdx.y;
    const int t0 = tt * 16;

    const int tid = threadIdx.x;
    const int wv = tid >> 6, ln = tid & 63;
    const int frow = ln & 15, quad = ln >> 4;

    const ushort* Pn  = P  + ((size_t)n * T_DIM + t0) * S_DIM;
    const ushort* Vtn = Vt + (size_t)n * D_HEAD * S_DIM;

    const int nsteps = (t0 + 47) >> 5;   // ceil((t0+16)/32)
    const int nclean = t0 >> 5;          // steps fully below diagonal

    floatx4 acc[8] = {};

    for (int sb = wv; sb < nsteps; sb += 4) {
        const int sbase = sb * 32;
        short8 a = *(const short8*)(Pn + (size_t)frow * S_DIM + sbase + quad * 8);
        if (sb >= nclean) {
            const int t = t0 + frow;
            #pragma unroll
            for (int j = 0; j < 8; ++j)
                if (sbase + quad * 8 + j > t) a[j] = 0;
        }
        #pragma unroll
        for (int dc = 0; dc < 8; ++dc) {
            const short8 b = *(const short8*)(Vtn + (size_t)(dc * 16 + frow) * S_DIM + sbase + quad * 8);
            acc[dc] = __builtin_amdgcn_mfma_f32_16x16x32_bf16(a, b, acc[dc], 0, 0, 0);
        }
    }

    // Cross-wave reduction. red[w][t_rel][d], d-stride 132 (2-way max = free).
    __shared__ float red[4][16][132];
    #pragma unroll
    for (int dc = 0; dc < 8; ++dc)
        #pragma unroll
        for (int r = 0; r < 4; ++r)
            red[wv][quad * 4 + r][dc * 16 + frow] = acc[dc][r];
    __syncthreads();

    // 512 float4 tasks: 16 t x 32 d4; 256 threads x 2. Coalesced stores.
    #pragma unroll
    for (int it = 0; it < 2; ++it) {
        int idx = tid + it * 256;
        int d4 = idx & 31;
        int tr = idx >> 5;
        float4 v;
        v.x = red[0][tr][d4 * 4 + 0] + red[1][tr][d4 * 4 + 0] + red[2][tr][d4 * 4 + 0] + red[3][tr][d4 * 4 + 0];
        v.y = red[0][tr][d4 * 4 + 1] + red[1][tr][d4 * 4 + 1] + red[2][tr][d4 * 4 + 1] + red[3][tr][d4 * 4 + 1];
        v.z = red[0][tr][d4 * 4 + 2] + red[1][tr][d4 * 4 + 2] + red[2][tr][d4 * 4 + 2] + red[3][tr][d4 * 4 + 2];
        v.w = red[0][tr][d4 * 4 + 3] + red[1][tr][d4 * 4 + 3] + red[2][tr][d4 * 4 + 3] + red[3][tr][d4 * 4 + 3];
        *(float4*)&O[((size_t)n * T_DIM + t0 + tr) * D_HEAD + d4 * 4] = v;
    }
}

// ---------------------------------------------------------------------------
extern "C" void kernel_launch(void* const* d_in, const int* in_sizes, int n_in,
                              void* d_out, int out_size, void* d_ws, size_t ws_size,
                              hipStream_t stream) {
    const float* Q    = (const float*)d_in[0];
    const float* K    = (const float*)d_in[1];
    const float* V    = (const float*)d_in[2];
    const float* sw_pre  = (const float*)d_in[4];
    const float* qw1_pre = (const float*)d_in[5];
    const float* qw2_pre = (const float*)d_in[6];
    const float* kw1_pre = (const float*)d_in[7];
    const float* kw2_pre = (const float*)d_in[8];
    const float* qdd_pre = (const float*)d_in[9];
    const float* kdd_pre = (const float*)d_in[10];
    const float* sw_post  = (const float*)d_in[11];
    const float* qw1_post = (const float*)d_in[12];
    const float* qw2_post = (const float*)d_in[13];
    const float* kw1_post = (const float*)d_in[14];
    const float* kw2_post = (const float*)d_in[15];
    const float* qdd_post = (const float*)d_in[16];
    const float* kdd_post = (const float*)d_in[17];

    // ws: L bf16 [32][1024][1024] = 64 MB, then Vt bf16 [32][128][1024] = 8 MB
    ushort* Lb = (ushort*)d_ws;
    ushort* Vt = (ushort*)((char*)d_ws + (size_t)N_HEADS * T_DIM * S_DIM * 2);
    float*  O  = (float*)d_out;

    // mats in d_out (8 MB of 16), consumed before av overwrites d_out
    ushort* mats  = (ushort*)d_out;
    ushort* Cpre  = mats + 0 * 1024 * 1024;
    ushort* Kpre  = mats + 1 * 1024 * 1024;
    ushort* Cpost = mats + 2 * 1024 * 1024;
    ushort* Kpost = mats + 3 * 1024 * 1024;

    mat4_kernel<<<dim3(1024, 4), 256, 0, stream>>>(
        sw_pre, qw1_pre, qw2_pre, qdd_pre, kw1_pre, kw2_pre, kdd_pre,
        sw_post, qw1_post, qw2_post, qdd_post, kw1_post, kw2_post, kdd_post, mats);
    vt_kernel<<<dim3(16, 32), 256, 0, stream>>>(V, Vt);

    qk_mfma<<<dim3(16, 16, 32), 256, 0, stream>>>(Q, K, Lb);
    proj_mfma<<<dim3(64, 32), 256, 0, stream>>>(Lb, Cpre, Kpre);
    softmax_kernel<<<dim3(1024, 32), 256, 0, stream>>>(Lb);
    proj_mfma<<<dim3(64, 32), 256, 0, stream>>>(Lb, Cpost, Kpost);
    av_mfma<<<dim3(64, 32), 256, 0, stream>>>(Lb, Vt, O);
}

// Round 7
// 338.464 us; speedup vs baseline: 1.0401x; 1.0134x over previous
//
#include <hip/hip_runtime.h>
#include <hip/hip_bf16.h>
#include <cstdint>
#include <cstddef>

#define T_DIM 1024
#define S_DIM 1024
#define N_HEADS 32
#define D_HEAD 128

typedef __attribute__((ext_vector_type(8))) short short8;
typedef __attribute__((ext_vector_type(4))) float floatx4;

__device__ inline int pack_bf16(float a, float b) {
    __hip_bfloat162 h = __float22bfloat162_rn(make_float2(a, b));
    int r; __builtin_memcpy(&r, &h, 4); return r;
}
__device__ inline ushort f2b(float x) {
    __hip_bfloat16 h = __float2bfloat16(x);
    ushort u; __builtin_memcpy(&u, &h, 2); return u;
}
__device__ inline float b2f(ushort u) {
    unsigned int v = ((unsigned int)u) << 16;
    float f; __builtin_memcpy(&f, &v, 4); return f;
}

// ---------------------------------------------------------------------------
// Vt[n][d][s] bf16 <- V[n][s][d] fp32.  64s x 128d tile per block.
// ---------------------------------------------------------------------------
__global__ __launch_bounds__(256) void vt_kernel(const float* __restrict__ V,
                                                 ushort* __restrict__ Vt) {
    const int s0 = blockIdx.x * 64;
    const int n  = blockIdx.y;
    __shared__ float lds[128 * 65];

    const int tid = threadIdx.x;
    const float* Vn = V + ((size_t)n * S_DIM + s0) * D_HEAD;

    #pragma unroll
    for (int it = 0; it < 8; ++it) {
        int idx = tid + it * 256;
        int d4 = idx & 31, s = idx >> 5;
        float4 v = *(const float4*)(Vn + (size_t)s * D_HEAD + d4 * 4);
        lds[(d4 * 4 + 0) * 65 + s] = v.x;
        lds[(d4 * 4 + 1) * 65 + s] = v.y;
        lds[(d4 * 4 + 2) * 65 + s] = v.z;
        lds[(d4 * 4 + 3) * 65 + s] = v.w;
    }
    __syncthreads();

    ushort* Vtn = Vt + (size_t)n * D_HEAD * S_DIM;
    #pragma unroll
    for (int it = 0; it < 4; ++it) {
        int idx = tid + it * 256;
        int sg = idx & 7, d = idx >> 3;
        const float* src = &lds[d * 65 + sg * 8];
        int4 o;
        o.x = pack_bf16(src[0], src[1]);
        o.y = pack_bf16(src[2], src[3]);
        o.z = pack_bf16(src[4], src[5]);
        o.w = pack_bf16(src[6], src[7]);
        *(int4*)&Vtn[(size_t)d * S_DIM + s0 + sg * 8] = o;
    }
}

// ---------------------------------------------------------------------------
// K1: logits (bf16) via MFMA, 64x64 causal tiles. Output staged through LDS
// (overlaid on dead Qt) for coalesced 16 B/lane row-major stores.
// ---------------------------------------------------------------------------
__global__ __launch_bounds__(256, 2) void qk_mfma(const float* __restrict__ Q,
                                                  const float* __restrict__ K,
                                                  ushort* __restrict__ Lb) {
    const int st = blockIdx.x;
    const int tt = blockIdx.y;
    const int n  = blockIdx.z;
    if (st > tt) return;

    __shared__ int Qt[64 * 64];
    __shared__ int Kt[64 * 64];

    const int tid = threadIdx.x;
    const int wv = tid >> 6, ln = tid & 63;
    const int frow = ln & 15, quad = ln >> 4;

    const float* Qn = Q + ((size_t)n * T_DIM + (size_t)tt * 64) * D_HEAD;
    const float* Kn = K + ((size_t)n * S_DIM + (size_t)st * 64) * D_HEAD;

    #pragma unroll
    for (int rep = 0; rep < 8; ++rep) {
        int idx = tid + rep * 256;
        int row = idx >> 5;
        int c4  = (idx & 31) * 4;
        int p   = c4 >> 1;
        int kb  = p >> 4, w = p & 15;
        int swz = 4 * (row & 3);
        float4 q = *(const float4*)(Qn + (size_t)row * D_HEAD + c4);
        int2 qv; qv.x = pack_bf16(q.x, q.y); qv.y = pack_bf16(q.z, q.w);
        *(int2*)&Qt[row * 64 + kb * 16 + (w ^ swz)] = qv;
        float4 k = *(const float4*)(Kn + (size_t)row * D_HEAD + c4);
        int2 kv; kv.x = pack_bf16(k.x, k.y); kv.y = pack_bf16(k.z, k.w);
        *(int2*)&Kt[row * 64 + kb * 16 + (w ^ swz)] = kv;
    }
    __syncthreads();

    const int swz = 4 * (frow & 3);
    floatx4 acc[4] = {};
    #pragma unroll
    for (int kb = 0; kb < 4; ++kb) {
        const short8 af = *(const short8*)&Qt[(wv * 16 + frow) * 64 + kb * 16 + ((quad * 4) ^ swz)];
        #pragma unroll
        for (int si = 0; si < 4; ++si) {
            const short8 bf = *(const short8*)&Kt[(si * 16 + frow) * 64 + kb * 16 + ((quad * 4) ^ swz)];
            acc[si] = __builtin_amdgcn_mfma_f32_16x16x32_bf16(af, bf, acc[si], 0, 0, 0);
        }
    }
    __syncthreads();                    // Qt dead -> reuse as output tile

    ushort* Ot = (ushort*)Qt;           // [64][72] bf16, 9 KB < 16 KB
    #pragma unroll
    for (int si = 0; si < 4; ++si)
        #pragma unroll
        for (int r = 0; r < 4; ++r)
            Ot[(wv * 16 + quad * 4 + r) * 72 + si * 16 + frow] = f2b(acc[si][r]);
    __syncthreads();

    #pragma unroll
    for (int it = 0; it < 2; ++it) {
        int idx = tid + it * 256;
        int row = idx >> 3, col = idx & 7;
        int4 v = *(const int4*)&Ot[row * 72 + col * 8];
        *(int4*)&Lb[((size_t)n * T_DIM + tt * 64 + row) * S_DIM + st * 64 + col * 8] = v;
    }
}

// ---------------------------------------------------------------------------
// Precompute all four 32x32 mixing-matrix families in one launch.
// ---------------------------------------------------------------------------
__global__ __launch_bounds__(256) void mat4_kernel(
        const float* __restrict__ sw_pre,  const float* __restrict__ qw1_pre,
        const float* __restrict__ qw2_pre, const float* __restrict__ qdd_pre,
        const float* __restrict__ kw1_pre, const float* __restrict__ kw2_pre,
        const float* __restrict__ kdd_pre,
        const float* __restrict__ sw_post,  const float* __restrict__ qw1_post,
        const float* __restrict__ qw2_post, const float* __restrict__ qdd_post,
        const float* __restrict__ kw1_post, const float* __restrict__ kw2_post,
        const float* __restrict__ kdd_post,
        ushort* __restrict__ mats) {
    const float *sw, *w1, *w2, *dd;
    float idadd;
    switch (blockIdx.y) {
        case 0:  sw = sw_pre;  w1 = qw1_pre;  w2 = qw2_pre;  dd = qdd_pre;  idadd = 1.0f; break;
        case 1:  sw = nullptr; w1 = kw1_pre;  w2 = kw2_pre;  dd = kdd_pre;  idadd = 0.0f; break;
        case 2:  sw = sw_post; w1 = qw1_post; w2 = qw2_post; dd = qdd_post; idadd = 1.0f; break;
        default: sw = nullptr; w1 = kw1_post; w2 = kw2_post; dd = kdd_post; idadd = 0.0f; break;
    }
    ushort* out = mats + (size_t)blockIdx.y * 1024 * 1024;

    const int t = blockIdx.x;
    const int tid = threadIdx.x;
    const int m = tid >> 3;
    const int n0 = (tid & 7) * 4;

    const float w2m0 = w2[t * 64 + m];
    const float w2m1 = w2[t * 64 + 32 + m];
    const float ddm  = dd[t * 32 + m];

    float v[4];
    #pragma unroll
    for (int j = 0; j < 4; ++j) {
        int n = n0 + j;
        float r = w1[t * 64 + n] * w2m0 + w1[t * 64 + 32 + n] * w2m1;
        if (sw) r += sw[n * 32 + m];
        if (n == m) r += idadd + ddm;
        v[j] = r;
    }
    int p0 = pack_bf16(v[0], v[1]);
    int p1 = pack_bf16(v[2], v[3]);
    int2 st = make_int2(p0, p1);
    *(int2*)&out[(size_t)t * 1024 + m * 32 + n0] = st;
}

// ---------------------------------------------------------------------------
// Fused cross-head projection via MFMA, in place on bf16 L. (unchanged)
// ---------------------------------------------------------------------------
__global__ __launch_bounds__(256, 2) void proj_mfma(ushort* __restrict__ Lb,
                                                    const ushort* __restrict__ Cmat,
                                                    const ushort* __restrict__ Kmat) {
    const int s0 = blockIdx.x * 16;
    const int t0 = blockIdx.y * 32;
    if (s0 > t0 + 31) return;

    __shared__ __align__(16) int lds[8192 + 10368];
    int* tileA = lds;
    int* tileB = lds + 8192;
    int* ldsD  = lds + 8192;

    const int tid = threadIdx.x;
    const int wv = tid >> 6, ln = tid & 63;

    #pragma unroll
    for (int rep = 0; rep < 2; ++rep) {
        int p  = tid + rep * 256;
        int tl = p >> 4, sl = p & 15;
        const ushort* xp = Lb + (size_t)(t0 + tl) * S_DIM + (s0 + sl);
        int packed[16];
        #pragma unroll
        for (int h = 0; h < 16; ++h) {
            ushort a = xp[(size_t)(2 * h)     * (T_DIM * S_DIM)];
            ushort b = xp[(size_t)(2 * h + 1) * (T_DIM * S_DIM)];
            packed[h] = (int)a | ((int)b << 16);
        }
        const int baseA = (tl * 16 + sl) * 16, swA = 4 * (sl & 3);
        const int baseB = sl * 516 + tl * 16,  swB = 4 * (tl & 3);
        #pragma unroll
        for (int h = 0; h < 16; ++h) {
            tileA[baseA + (h ^ swA)] = packed[h];
            tileB[baseB + (h ^ swB)] = packed[h];
        }
    }
    __syncthreads();

    const int frow = ln & 15;
    const int fkg  = ln >> 4;

    floatx4 dk[4][2][2];
    #pragma unroll
    for (int si = 0; si < 4; ++si) {
        const int s_l = wv * 4 + si;
        const int s_g = s0 + s_l;
        #pragma unroll
        for (int mh = 0; mh < 2; ++mh) {
            const short8 af = *(const short8*)(Kmat + (size_t)s_g * 1024 + (mh * 16 + frow) * 32 + fkg * 8);
            #pragma unroll
            for (int tc = 0; tc < 2; ++tc) {
                const int* bp = &tileB[s_l * 516 + (tc * 16 + frow) * 16 + ((4 * fkg) ^ (4 * (frow & 3)))];
                const short8 bf = *(const short8*)bp;
                floatx4 z = {0.f, 0.f, 0.f, 0.f};
                dk[si][mh][tc] = __builtin_amdgcn_mfma_f32_16x16x32_bf16(af, bf, z, 0, 0, 0);
            }
        }
    }
    __syncthreads();

    #pragma unroll
    for (int mh = 0; mh < 2; ++mh) {
        #pragma unroll
        for (int si = 0; si < 4; ++si) {
            const int s_l = wv * 4 + si;
            #pragma unroll
            for (int tc = 0; tc < 2; ++tc) {
                const int tl = tc * 16 + frow;
                const int off = tl * 324 + s_l * 20 + fkg * 4;
                *(floatx4*)&ldsD[off] = dk[si][mh][tc];
            }
        }
        __syncthreads();

        #pragma unroll
        for (int ti = 0; ti < 8; ++ti) {
            const int tl = wv * 8 + ti;
            const int tg = t0 + tl;
            const short8 af = *(const short8*)&tileA[(tl * 16 + frow) * 16 + ((4 * fkg) ^ (4 * (frow & 3)))];
            const short8 bf = *(const short8*)(Cmat + (size_t)tg * 1024 + (mh * 16 + frow) * 32 + fkg * 8);
            floatx4 z = {0.f, 0.f, 0.f, 0.f};
            floatx4 d = __builtin_amdgcn_mfma_f32_16x16x32_bf16(af, bf, z, 0, 0, 0);

            const int m_l = frow;
            const int s_base = fkg * 4;
            float v[4];
            #pragma unroll
            for (int r = 0; r < 4; ++r) {
                float kadd = ((const float*)ldsD)[tl * 324 + (s_base + r) * 20 + m_l];
                float val = d[r] + kadd;
                v[r] = (s0 + s_base + r > tg) ? 0.0f : val;
            }
            uint2 st;
            st.x = (unsigned)pack_bf16(v[0], v[1]);
            st.y = (unsigned)pack_bf16(v[2], v[3]);
            *(uint2*)&Lb[((size_t)(mh * 16 + m_l) * T_DIM + tg) * S_DIM + s0 + s_base] = st;
        }
        __syncthreads();
    }
}

// ---------------------------------------------------------------------------
// K3: softmax over s in [0, t], in place on bf16 L. Causal skip: threads with
// i0 > t neither load nor store (halves HBM traffic). Beyond-t region is left
// unwritten -> av masks it in-register.
// ---------------------------------------------------------------------------
__global__ __launch_bounds__(256) void softmax_kernel(ushort* __restrict__ Lb) {
    const int t = blockIdx.x;
    const int n = blockIdx.y;
    ushort* row = Lb + ((size_t)n * T_DIM + t) * S_DIM;
    const int tid = threadIdx.x;
    const int i0 = tid * 4;
    const bool act = (i0 <= t);

    float v[4] = {-INFINITY, -INFINITY, -INFINITY, -INFINITY};
    if (act) {
        uint2 raw = *(const uint2*)&row[i0];
        v[0] = b2f((ushort)(raw.x & 0xffff));
        v[1] = b2f((ushort)(raw.x >> 16));
        v[2] = b2f((ushort)(raw.y & 0xffff));
        v[3] = b2f((ushort)(raw.y >> 16));
        #pragma unroll
        for (int j = 0; j < 4; ++j)
            if (i0 + j > t) v[j] = -INFINITY;
    }

    float m = fmaxf(fmaxf(v[0], v[1]), fmaxf(v[2], v[3]));
    #pragma unroll
    for (int off = 32; off > 0; off >>= 1) m = fmaxf(m, __shfl_xor(m, off));

    __shared__ float redm[4];
    __shared__ float reds[4];
    if ((tid & 63) == 0) redm[tid >> 6] = m;
    __syncthreads();
    m = fmaxf(fmaxf(redm[0], redm[1]), fmaxf(redm[2], redm[3]));

    float e[4];
    float ssum = 0.0f;
    #pragma unroll
    for (int j = 0; j < 4; ++j) {
        e[j] = (v[j] > -INFINITY) ? expf(v[j] - m) : 0.0f;
        ssum += e[j];
    }
    #pragma unroll
    for (int off = 32; off > 0; off >>= 1) ssum += __shfl_xor(ssum, off);
    if ((tid & 63) == 0) reds[tid >> 6] = ssum;
    __syncthreads();
    ssum = reds[0] + reds[1] + reds[2] + reds[3];
    const float inv = 1.0f / ssum;

    if (act) {
        uint2 st;
        st.x = (unsigned)pack_bf16(e[0] * inv, e[1] * inv);
        st.y = (unsigned)pack_bf16(e[2] * inv, e[3] * inv);
        *(uint2*)&row[i0] = st;
    }
}

// ---------------------------------------------------------------------------
// K5: O = P V via MFMA. Block = 4 waves on one (n, 16t) tile. P is staged
// through LDS in 256-s chunks with fully-coalesced 512 B/row loads; A-frags
// come from swizzled LDS (conflict-free); B-frags direct from L2-hot Vt.
// Cross-wave reduction in bf16 LDS, coalesced float4 stores.
// ---------------------------------------------------------------------------
__global__ __launch_bounds__(256, 4) void av_mfma(const ushort* __restrict__ P,
                                                  const ushort* __restrict__ Vt,
                                                  float* __restrict__ O) {
    const int tt = 63 - blockIdx.x;      // big tiles first
    const int n  = blockIdx.y;
    const int t0 = tt * 16;

    __shared__ __align__(16) int Pl[16 * 128];      // 8 KB, [t][sp ^ swz]
    __shared__ ushort red[4][16][136];              // 17 KB bf16 partials

    const int tid = threadIdx.x;
    const int wv = tid >> 6, ln = tid & 63;
    const int frow = ln & 15, quad = ln >> 4;

    const ushort* Pn  = P  + ((size_t)n * T_DIM + t0) * S_DIM;
    const ushort* Vtn = Vt + (size_t)n * D_HEAD * S_DIM;

    const int nsteps  = (t0 + 47) >> 5;   // ceil((t0+16)/32)
    const int nclean  = t0 >> 5;          // steps fully below diagonal
    const int nchunks = (nsteps + 7) >> 3;

    floatx4 acc[8] = {};

    for (int cb = 0; cb < nchunks; ++cb) {
        const int cbase = cb * 256;
        __syncthreads();
        // coop load P[16][256] bf16 -> LDS; lanes 0-31 = 512 B of one row.
        #pragma unroll
        for (int it = 0; it < 2; ++it) {
            int idx = tid + it * 256;
            int row = idx >> 5, col = idx & 31;
            int4 v = *(const int4*)(Pn + (size_t)row * S_DIM + cbase + col * 8);
            *(int4*)&Pl[row * 128 + ((col * 4) ^ (4 * (row & 3)))] = v;
        }
        __syncthreads();

        const int sEnd = min(nsteps, cb * 8 + 8);
        #pragma unroll
        for (int k = 0; k < 2; ++k) {
            const int sb = cb * 8 + wv * 2 + k;
            if (sb < sEnd) {
                const int sloc = (sb & 7) * 16;
                short8 a = *(const short8*)&Pl[frow * 128 + ((sloc + quad * 4) ^ (4 * (frow & 3)))];
                if (sb >= nclean) {
                    const int t = t0 + frow;
                    const int sg0 = sb * 32 + quad * 8;
                    #pragma unroll
                    for (int j = 0; j < 8; ++j)
                        if (sg0 + j > t) a[j] = 0;
                }
                const int sbase = sb * 32;
                #pragma unroll
                for (int dc = 0; dc < 8; ++dc) {
                    const short8 b = *(const short8*)(Vtn + (size_t)(dc * 16 + frow) * S_DIM + sbase + quad * 8);
                    acc[dc] = __builtin_amdgcn_mfma_f32_16x16x32_bf16(a, b, acc[dc], 0, 0, 0);
                }
            }
        }
    }

    #pragma unroll
    for (int dc = 0; dc < 8; ++dc)
        #pragma unroll
        for (int r = 0; r < 4; ++r)
            red[wv][quad * 4 + r][dc * 16 + frow] = f2b(acc[dc][r]);
    __syncthreads();

    #pragma unroll
    for (int it = 0; it < 2; ++it) {
        int idx = tid + it * 256;
        int d4 = idx & 31, tr = idx >> 5;
        float4 v;
        v.x = b2f(red[0][tr][d4 * 4 + 0]) + b2f(red[1][tr][d4 * 4 + 0]) + b2f(red[2][tr][d4 * 4 + 0]) + b2f(red[3][tr][d4 * 4 + 0]);
        v.y = b2f(red[0][tr][d4 * 4 + 1]) + b2f(red[1][tr][d4 * 4 + 1]) + b2f(red[2][tr][d4 * 4 + 1]) + b2f(red[3][tr][d4 * 4 + 1]);
        v.z = b2f(red[0][tr][d4 * 4 + 2]) + b2f(red[1][tr][d4 * 4 + 2]) + b2f(red[2][tr][d4 * 4 + 2]) + b2f(red[3][tr][d4 * 4 + 2]);
        v.w = b2f(red[0][tr][d4 * 4 + 3]) + b2f(red[1][tr][d4 * 4 + 3]) + b2f(red[2][tr][d4 * 4 + 3]) + b2f(red[3][tr][d4 * 4 + 3]);
        *(float4*)&O[((size_t)n * T_DIM + t0 + tr) * D_HEAD + d4 * 4] = v;
    }
}

// ---------------------------------------------------------------------------
extern "C" void kernel_launch(void* const* d_in, const int* in_sizes, int n_in,
                              void* d_out, int out_size, void* d_ws, size_t ws_size,
                              hipStream_t stream) {
    const float* Q    = (const float*)d_in[0];
    const float* K    = (const float*)d_in[1];
    const float* V    = (const float*)d_in[2];
    const float* sw_pre  = (const float*)d_in[4];
    const float* qw1_pre = (const float*)d_in[5];
    const float* qw2_pre = (const float*)d_in[6];
    const float* kw1_pre = (const float*)d_in[7];
    const float* kw2_pre = (const float*)d_in[8];
    const float* qdd_pre = (const float*)d_in[9];
    const float* kdd_pre = (const float*)d_in[10];
    const float* sw_post  = (const float*)d_in[11];
    const float* qw1_post = (const float*)d_in[12];
    const float* qw2_post = (const float*)d_in[13];
    const float* kw1_post = (const float*)d_in[14];
    const float* kw2_post = (const float*)d_in[15];
    const float* qdd_post = (const float*)d_in[16];
    const float* kdd_post = (const float*)d_in[17];

    // ws: L bf16 [32][1024][1024] = 64 MB, then Vt bf16 [32][128][1024] = 8 MB
    ushort* Lb = (ushort*)d_ws;
    ushort* Vt = (ushort*)((char*)d_ws + (size_t)N_HEADS * T_DIM * S_DIM * 2);
    float*  O  = (float*)d_out;

    // mats in d_out (8 MB of 16), consumed before av overwrites d_out
    ushort* mats  = (ushort*)d_out;
    ushort* Cpre  = mats + 0 * 1024 * 1024;
    ushort* Kpre  = mats + 1 * 1024 * 1024;
    ushort* Cpost = mats + 2 * 1024 * 1024;
    ushort* Kpost = mats + 3 * 1024 * 1024;

    mat4_kernel<<<dim3(1024, 4), 256, 0, stream>>>(
        sw_pre, qw1_pre, qw2_pre, qdd_pre, kw1_pre, kw2_pre, kdd_pre,
        sw_post, qw1_post, qw2_post, qdd_post, kw1_post, kw2_post, kdd_post, mats);
    vt_kernel<<<dim3(16, 32), 256, 0, stream>>>(V, Vt);

    qk_mfma<<<dim3(16, 16, 32), 256, 0, stream>>>(Q, K, Lb);
    proj_mfma<<<dim3(64, 32), 256, 0, stream>>>(Lb, Cpre, Kpre);
    softmax_kernel<<<dim3(1024, 32), 256, 0, stream>>>(Lb);
    proj_mfma<<<dim3(64, 32), 256, 0, stream>>>(Lb, Cpost, Kpost);
    av_mfma<<<dim3(64, 32), 256, 0, stream>>>(Lb, Vt, O);
}